// Round 2
// baseline (1249.992 us; speedup 1.0000x reference)
//
#include <hip/hip_runtime.h>
#include <hip/hip_bf16.h>
#include <cstdint>
#include <cstddef>

#define TOKENS   32768
#define DDIM     4096
#define NEXP     64
#define N2       65536       // TOKENS*2 slots
#define CAPACITY 1126        // int(32768*1.1*2/64)
#define DSPLIT   8           // k-split of D
#define DPART    (DDIM / DSPLIT)   // 512

// ---------------- workspace byte offsets ----------------
// part    : float[DSPLIT][TOKENS][64] partial logits       @ 0       (64 MiB)
// p_flat  : float[N2]                                      @ 64 MiB
// e_flat  : int[N2]                                        @ +256 KiB
// psum    : float[64]                                      @ +512 KiB
// counts  : int[64]                                        @ +512 KiB + 256 B
#define WS_PART  0
#define WS_PFLAT (64u << 20)
#define WS_EFLAT ((64u << 20) + 262144u)
#define WS_PSUM  ((64u << 20) + 524288u)
#define WS_CNT   ((64u << 20) + 524288u + 256u)

// ---------------- zero dispatch+combine and psum ----------------
__global__ void zero_kernel(float* __restrict__ dc, float* __restrict__ psum) {
    int idx = blockIdx.x * blockDim.x + threadIdx.x;
    float4 z = make_float4(0.f, 0.f, 0.f, 0.f);
    const int n4 = (2 * TOKENS * NEXP) / 4;   // dispatch+combine contiguous
    for (int i = idx; i < n4; i += gridDim.x * blockDim.x)
        ((float4*)dc)[i] = z;
    if (idx < NEXP) psum[idx] = 0.f;
}

// ---------------- partial logits GEMM: no LDS, W via scalar loads ----------
// grid = 128 token-groups x 8 d-parts = 1024 blocks, 256 threads.
// One token per lane; acc[64] in VGPRs; W rows are wave-uniform -> s_load +
// v_fma with SGPR operand. Two-level accumulation (32-k chunks) to keep
// rounding error in the same class as round-1 (which had zero top-2 flips).
__launch_bounds__(256, 2)
__global__ void gemm_partial(const float* __restrict__ x, const float* __restrict__ W,
                             float* __restrict__ part) {
    const int tid = threadIdx.x;
    const int dh  = blockIdx.x & (DSPLIT - 1);
    const int tg  = blockIdx.x >> 3;
    const int t   = tg * 256 + tid;
    const float* xrow = x + (size_t)t * DDIM + dh * DPART;
    const float* wq   = W + dh * DPART;          // row e: wq + e*DDIM

    float tot[64];
#pragma unroll
    for (int e = 0; e < 64; ++e) tot[e] = 0.f;

    for (int c = 0; c < DPART; c += 32) {        // 16 chunks
        float xr[32];
#pragma unroll
        for (int j = 0; j < 32; j += 4) {
            float4 v = *(const float4*)&xrow[c + j];
            xr[j] = v.x; xr[j+1] = v.y; xr[j+2] = v.z; xr[j+3] = v.w;
        }
#pragma unroll
        for (int e = 0; e < 64; ++e) {
            const float* wrow = wq + (size_t)e * DDIM + c;   // uniform -> SGPR
            float s0 = 0.f, s1 = 0.f;                        // 2 chains for ILP
#pragma unroll
            for (int j = 0; j < 32; j += 2) {
                s0 = fmaf(xr[j],     wrow[j],     s0);
                s1 = fmaf(xr[j + 1], wrow[j + 1], s1);
            }
            tot[e] += (s0 + s1);
        }
    }
    float* o = part + ((size_t)dh * TOKENS + t) * 64;
#pragma unroll
    for (int e = 0; e < 64; e += 4)
        *(float4*)&o[e] = make_float4(tot[e], tot[e+1], tot[e+2], tot[e+3]);
}

// ---------------- combine partials + softmax + top2 + probs + psum ---------
// 256 blocks x 256 threads; block handles 128 tokens.
__launch_bounds__(256, 2)
__global__ void combine_kernel(const float* __restrict__ part,
                               float* __restrict__ probs_out,
                               float* __restrict__ p_flat,
                               int* __restrict__ e_flat,
                               float* __restrict__ psum) {
    __shared__ __align__(16) float L[128][68];
    __shared__ float red[256];
    const int tid  = threadIdx.x;
    const int tok0 = blockIdx.x * 128;
    const size_t base = (size_t)tok0 * 64;

    // pairwise-tree sum of the 8 partials, coalesced float4 reads
#pragma unroll
    for (int i = 0; i < 8; ++i) {
        int idx4 = i * 256 + tid;                 // float4 index in 8192-float slab
        const float4* p0 = (const float4*)(part + 0ull * TOKENS * 64 + base) + idx4;
        const float4* p1 = (const float4*)(part + 1ull * TOKENS * 64 + base) + idx4;
        const float4* p2 = (const float4*)(part + 2ull * TOKENS * 64 + base) + idx4;
        const float4* p3 = (const float4*)(part + 3ull * TOKENS * 64 + base) + idx4;
        const float4* p4 = (const float4*)(part + 4ull * TOKENS * 64 + base) + idx4;
        const float4* p5 = (const float4*)(part + 5ull * TOKENS * 64 + base) + idx4;
        const float4* p6 = (const float4*)(part + 6ull * TOKENS * 64 + base) + idx4;
        const float4* p7 = (const float4*)(part + 7ull * TOKENS * 64 + base) + idx4;
        float4 a0 = *p0, a1 = *p1, a2 = *p2, a3 = *p3, a4 = *p4, a5 = *p5, a6 = *p6, a7 = *p7;
        float4 s;
        s.x = ((a0.x + a1.x) + (a2.x + a3.x)) + ((a4.x + a5.x) + (a6.x + a7.x));
        s.y = ((a0.y + a1.y) + (a2.y + a3.y)) + ((a4.y + a5.y) + (a6.y + a7.y));
        s.z = ((a0.z + a1.z) + (a2.z + a3.z)) + ((a4.z + a5.z) + (a6.z + a7.z));
        s.w = ((a0.w + a1.w) + (a2.w + a3.w)) + ((a4.w + a5.w) + (a6.w + a7.w));
        int row = idx4 >> 4, col = (idx4 & 15) * 4;
        *(float4*)&L[row][col] = s;
    }
    __syncthreads();

    if (tid < 128) {
        const int t = tid;
        float m = -INFINITY;
#pragma unroll
        for (int e = 0; e < 64; ++e) m = fmaxf(m, L[t][e]);
        float s = 0.f;
        float v[64];
#pragma unroll
        for (int e = 0; e < 64; ++e) { v[e] = expf(L[t][e] - m); s += v[e]; }
        float p1 = -1.f, p2 = -1.f; int i1 = 0, i2 = 0;
#pragma unroll
        for (int e = 0; e < 64; ++e) {
            float p = v[e] / s;
            L[t][e] = p;
            if (p > p1)      { p2 = p1; i2 = i1; p1 = p; i1 = e; }
            else if (p > p2) { p2 = p;  i2 = e; }
        }
        float rs = p1 + p2;
        int g = tok0 + t;
        p_flat[2 * g]     = p1 / rs;
        p_flat[2 * g + 1] = p2 / rs;
        e_flat[2 * g]     = i1;
        e_flat[2 * g + 1] = i2;
    }
    __syncthreads();

    // coalesced probs write
#pragma unroll
    for (int i = 0; i < 8; ++i) {
        int idx4 = i * 256 + tid;
        int row = idx4 >> 4, col = (idx4 & 15) * 4;
        ((float4*)(probs_out + base))[idx4] = *(const float4*)&L[row][col];
    }

    // per-expert column partial sums
    float acc = 0.f;
    {
        int e = tid & 63, rg = (tid >> 6) * 32;
#pragma unroll
        for (int r = 0; r < 32; ++r) acc += L[rg + r][e];
    }
    red[tid] = acc;
    __syncthreads();
    if (tid < 64) {
        float v = red[tid] + red[tid + 64] + red[tid + 128] + red[tid + 192];
        atomicAdd(&psum[tid], v);
    }
}

// ---------------- per-expert capacity ranking + scatter ----------------
// 64 blocks (one per expert) x 256 threads. If n <= CAPACITY every assigned
// slot is kept -> skip the sort entirely (the common case: mean n = 1024).
// Else bitonic-sort next_pow2(n) packed keys (desc prob, asc slot).
__launch_bounds__(256, 2)
__global__ void expert_sort_kernel(const float* __restrict__ p_flat,
                                   const int* __restrict__ e_flat,
                                   float* __restrict__ dispatch,
                                   float* __restrict__ combine,
                                   int* __restrict__ counts) {
    __shared__ unsigned long long keys[4096];
    __shared__ int cnt;
    const int tid = threadIdx.x;
    const int e   = blockIdx.x;

    if (tid == 0) cnt = 0;
    __syncthreads();

    for (int i4 = tid; i4 < N2 / 4; i4 += 256) {
        int4 ev = ((const int4*)e_flat)[i4];
        int slot = i4 * 4;
#pragma unroll
        for (int j = 0; j < 4; ++j) {
            int ee = (j == 0) ? ev.x : (j == 1) ? ev.y : (j == 2) ? ev.z : ev.w;
            if (ee == e) {
                float p = p_flat[slot + j];
                int pos = atomicAdd(&cnt, 1);
                if (pos < 4096)
                    keys[pos] = ((unsigned long long)__float_as_uint(p) << 32) |
                                (unsigned long long)(0xFFFFFFFFu - (unsigned)(slot + j));
            }
        }
    }
    __syncthreads();
    const int n = cnt;

    if (n > CAPACITY) {
        int m = 2048;                    // n > 1126 -> m is 2048 or 4096
        while (m < n) m <<= 1;
        for (int i = tid; i < m; i += 256)
            if (i >= n) keys[i] = 0ull;
        __syncthreads();

        for (int k = 2; k <= m; k <<= 1) {
            for (int j = k >> 1; j > 0; j >>= 1) {
                for (int i = tid; i < m; i += 256) {
                    int ixj = i ^ j;
                    if (ixj > i) {
                        bool desc = ((i & k) == 0);
                        unsigned long long a = keys[i], b = keys[ixj];
                        bool sw = desc ? (a < b) : (a > b);
                        if (sw) { keys[i] = b; keys[ixj] = a; }
                    }
                }
                __syncthreads();
            }
        }
    }

    int lim = n < CAPACITY ? n : CAPACITY;
    for (int pos = tid; pos < lim; pos += 256) {
        unsigned long long key = keys[pos];
        unsigned slot = 0xFFFFFFFFu - (unsigned)(key & 0xFFFFFFFFull);
        float p = __uint_as_float((unsigned)(key >> 32));
        int token = (int)(slot >> 1);
        dispatch[(size_t)token * 64 + e] = 1.0f;
        combine [(size_t)token * 64 + e] = p;
    }
    if (tid == 0) counts[e] = n;
}

// ---------------- aux loss ----------------
__global__ void aux_kernel(const float* __restrict__ psum,
                           const int* __restrict__ counts,
                           float* __restrict__ out_aux) {
    int tid = threadIdx.x;   // 64 threads
    float v = (psum[tid] / (float)TOKENS) * ((float)counts[tid] / (float)N2);
    for (int off = 32; off > 0; off >>= 1) v += __shfl_down(v, off, 64);
    if (tid == 0) *out_aux = v * (float)NEXP;
}

extern "C" void kernel_launch(void* const* d_in, const int* in_sizes, int n_in,
                              void* d_out, int out_size, void* d_ws, size_t ws_size,
                              hipStream_t stream) {
    (void)in_sizes; (void)n_in; (void)out_size; (void)ws_size;

    const float* x = (const float*)d_in[0];
    const float* W = (const float*)d_in[1];

    float* out      = (float*)d_out;
    float* dispatch = out;                         // [32768*64]
    float* combine  = out + (size_t)TOKENS * NEXP; // [32768*64]
    float* probs    = out + (size_t)2 * TOKENS * NEXP;
    float* aux      = out + (size_t)3 * TOKENS * NEXP;

    char*  ws     = (char*)d_ws;
    float* part   = (float*)(ws + WS_PART);
    float* p_flat = (float*)(ws + WS_PFLAT);
    int*   e_flat = (int*)  (ws + WS_EFLAT);
    float* psum   = (float*)(ws + WS_PSUM);
    int*   counts = (int*)  (ws + WS_CNT);

    zero_kernel<<<1024, 256, 0, stream>>>(dispatch, psum);
    gemm_partial<<<1024, 256, 0, stream>>>(x, W, part);
    combine_kernel<<<256, 256, 0, stream>>>(part, probs, p_flat, e_flat, psum);
    expert_sort_kernel<<<64, 256, 0, stream>>>(p_flat, e_flat, dispatch, combine, counts);
    aux_kernel<<<1, 64, 0, stream>>>(psum, counts, aux);
}

// Round 3
// 994.867 us; speedup vs baseline: 1.2564x; 1.2564x over previous
//
#include <hip/hip_runtime.h>
#include <hip/hip_bf16.h>
#include <cstdint>
#include <cstddef>

#define TOKENS   32768
#define DDIM     4096
#define NEXP     64
#define N2       65536       // TOKENS*2 slots
#define CAPACITY 1126        // int(32768*1.1*2/64)
#define KSPLIT   2
#define KHALF    (DDIM / KSPLIT)   // 2048
#define BK       32
#define TT       128         // tokens per gemm block

// ---------------- workspace byte offsets ----------------
// part    : float[KSPLIT][TOKENS][64] partial logits       @ 0       (16 MiB)
// p_flat  : float[N2]                                      @ 16 MiB
// e_flat  : int[N2]                                        @ +256 KiB
// psum    : float[64]                                      @ +512 KiB
// counts  : int[64]                                        @ +512 KiB + 256 B
#define WS_PART  0
#define WS_PFLAT (16u << 20)
#define WS_EFLAT ((16u << 20) + 262144u)
#define WS_PSUM  ((16u << 20) + 524288u)
#define WS_CNT   ((16u << 20) + 524288u + 256u)

// ---------------- zero dispatch+combine and psum ----------------
__global__ void zero_kernel(float* __restrict__ dc, float* __restrict__ psum) {
    int idx = blockIdx.x * blockDim.x + threadIdx.x;
    float4 z = make_float4(0.f, 0.f, 0.f, 0.f);
    const int n4 = (2 * TOKENS * NEXP) / 4;   // dispatch+combine contiguous
    for (int i = idx; i < n4; i += gridDim.x * blockDim.x)
        ((float4*)dc)[i] = z;
    if (idx < NEXP) psum[idx] = 0.f;
}

// ---------------- logits GEMM, DS-pipe-optimized ----------------
// grid = 512 (256 token-groups x 2 k-halves), block = 128 threads (2 waves).
// Tile 128 tok x 64 exp x 2048 k; thread tile 8x8 (the DS-pipe sweet spot:
// (m+e)=16 ds_read_b128 feed 256 FMA-inst per 4k -> DS-bound at ~164 us).
// Staging: global_load_lds width 16 (async, no DS-write instrs), double-
// buffered; prefetch issued AFTER the barrier so the barrier's vmcnt(0)
// only drains chunk-old loads. XOR column swizzle (key = row>>3) makes the
// unpadded [row][32] layout conflict-free for the strided 8-row reads.
__launch_bounds__(128, 1)
__global__ void gemm_logits(const float* __restrict__ x, const float* __restrict__ W,
                            float* __restrict__ part) {
    __shared__ __align__(16) float xs[2][TT * BK];   // 2 x 16 KiB
    __shared__ __align__(16) float wt[2][NEXP * BK]; // 2 x 8 KiB

    const int tid  = threadIdx.x;
    const int lane = tid & 63;
    const int wv   = tid >> 6;          // 0..1
    const int tx   = tid & 7;           // expert octet: e = tx*8 + j
    const int ty   = tid >> 3;          // token octet: t = ty*8 + i  (0..15)
    const int kh   = blockIdx.x & 1;
    const int tok0 = (blockIdx.x >> 1) * TT;
    const int d0b  = kh * KHALF;

    const int srow = lane >> 3;         // 0..7 within one staging instr
    const int scol = lane & 7;          // 16B-granule within row

    // async-stage chunk c into buffer p (x: 16 instrs, W: 8, split by wave)
    auto stage = [&](int p, int c) {
#pragma unroll
        for (int qq = 0; qq < 8; ++qq) {            // x rows q*8 .. q*8+7
            int q = wv * 8 + qq;                    // 0..15
            int r = q * 8 + srow;
            const float* g = x + (size_t)(tok0 + r) * DDIM + d0b + c * BK
                               + 4 * (scol ^ (q & 7));
            __builtin_amdgcn_global_load_lds(
                (const __attribute__((address_space(1))) void*)g,
                (__attribute__((address_space(3))) void*)&xs[p][q * 8 * BK],
                16, 0, 0);
        }
#pragma unroll
        for (int qq = 0; qq < 4; ++qq) {            // W rows q*8 .. q*8+7
            int q = wv * 4 + qq;                    // 0..7
            int e = q * 8 + srow;
            const float* g = W + (size_t)e * DDIM + d0b + c * BK
                               + 4 * (scol ^ (q & 7));
            __builtin_amdgcn_global_load_lds(
                (const __attribute__((address_space(1))) void*)g,
                (__attribute__((address_space(3))) void*)&wt[p][q * 8 * BK],
                16, 0, 0);
        }
    };

    float tot[8][8];
#pragma unroll
    for (int i = 0; i < 8; ++i)
#pragma unroll
        for (int j = 0; j < 8; ++j) tot[i][j] = 0.f;

    stage(0, 0);

    const int NCHUNK = KHALF / BK;   // 64
    for (int c = 0; c < NCHUNK; ++c) {
        const int p = c & 1;
        __syncthreads();             // drains vmcnt: buf p ready; buf p^1 reads done
        if (c + 1 < NCHUNK) stage(p ^ 1, c + 1);

#pragma unroll
        for (int g = 0; g < 8; ++g) {
            float4 xr[8], wr[8];
#pragma unroll
            for (int i = 0; i < 8; ++i)
                xr[i] = *(const float4*)&xs[p][(ty * 8 + i) * BK + 4 * (g ^ (ty & 7))];
#pragma unroll
            for (int j = 0; j < 8; ++j)
                wr[j] = *(const float4*)&wt[p][(tx * 8 + j) * BK + 4 * (g ^ (tx & 7))];
#pragma unroll
            for (int i = 0; i < 8; ++i)
#pragma unroll
                for (int j = 0; j < 8; ++j) {
                    tot[i][j] = fmaf(xr[i].x, wr[j].x, tot[i][j]);
                    tot[i][j] = fmaf(xr[i].y, wr[j].y, tot[i][j]);
                    tot[i][j] = fmaf(xr[i].z, wr[j].z, tot[i][j]);
                    tot[i][j] = fmaf(xr[i].w, wr[j].w, tot[i][j]);
                }
        }
    }

    // epilogue: part[kh][tok][e], lanes tx 0..7 -> contiguous 128B per row
    float* o = part + ((size_t)kh * TOKENS + tok0) * 64;
#pragma unroll
    for (int i = 0; i < 8; ++i) {
        int row = ty * 8 + i;
        *(float4*)&o[(size_t)row * 64 + tx * 8 + 0] =
            make_float4(tot[i][0], tot[i][1], tot[i][2], tot[i][3]);
        *(float4*)&o[(size_t)row * 64 + tx * 8 + 4] =
            make_float4(tot[i][4], tot[i][5], tot[i][6], tot[i][7]);
    }
}

// ---------------- combine partials + softmax + top2 + probs + psum ---------
// 256 blocks x 256 threads; block handles 128 tokens.
__launch_bounds__(256, 2)
__global__ void combine_kernel(const float* __restrict__ part,
                               float* __restrict__ probs_out,
                               float* __restrict__ p_flat,
                               int* __restrict__ e_flat,
                               float* __restrict__ psum) {
    __shared__ __align__(16) float L[128][68];
    __shared__ float red[256];
    const int tid  = threadIdx.x;
    const int tok0 = blockIdx.x * 128;
    const size_t base = (size_t)tok0 * 64;

#pragma unroll
    for (int i = 0; i < 8; ++i) {
        int idx4 = i * 256 + tid;                 // float4 index in 8192-float slab
        float4 a0 = ((const float4*)(part + 0ull * TOKENS * 64 + base))[idx4];
        float4 a1 = ((const float4*)(part + 1ull * TOKENS * 64 + base))[idx4];
        float4 s = make_float4(a0.x + a1.x, a0.y + a1.y, a0.z + a1.z, a0.w + a1.w);
        int row = idx4 >> 4, col = (idx4 & 15) * 4;
        *(float4*)&L[row][col] = s;
    }
    __syncthreads();

    if (tid < 128) {
        const int t = tid;
        float m = -INFINITY;
#pragma unroll
        for (int e = 0; e < 64; ++e) m = fmaxf(m, L[t][e]);
        float s = 0.f;
#pragma unroll
        for (int e = 0; e < 64; ++e) {
            float v = expf(L[t][e] - m);
            L[t][e] = v;
            s += v;
        }
        float p1 = -1.f, p2 = -1.f; int i1 = 0, i2 = 0;
#pragma unroll
        for (int e = 0; e < 64; ++e) {
            float p = L[t][e] / s;
            L[t][e] = p;
            if (p > p1)      { p2 = p1; i2 = i1; p1 = p; i1 = e; }
            else if (p > p2) { p2 = p;  i2 = e; }
        }
        float rs = p1 + p2;
        int g = tok0 + t;
        p_flat[2 * g]     = p1 / rs;
        p_flat[2 * g + 1] = p2 / rs;
        e_flat[2 * g]     = i1;
        e_flat[2 * g + 1] = i2;
    }
    __syncthreads();

    // coalesced probs write
#pragma unroll
    for (int i = 0; i < 8; ++i) {
        int idx4 = i * 256 + tid;
        int row = idx4 >> 4, col = (idx4 & 15) * 4;
        ((float4*)(probs_out + base))[idx4] = *(const float4*)&L[row][col];
    }

    // per-expert column partial sums
    float acc = 0.f;
    {
        int e = tid & 63, rg = (tid >> 6) * 32;
#pragma unroll
        for (int r = 0; r < 32; ++r) acc += L[rg + r][e];
    }
    red[tid] = acc;
    __syncthreads();
    if (tid < 64) {
        float v = red[tid] + red[tid + 64] + red[tid + 128] + red[tid + 192];
        atomicAdd(&psum[tid], v);
    }
}

// ---------------- per-expert capacity ranking + scatter ----------------
// 64 blocks (one per expert) x 256 threads. If n <= CAPACITY every assigned
// slot is kept -> skip the sort (the common case: counts ~ 1024 +- 32).
__launch_bounds__(256, 2)
__global__ void expert_sort_kernel(const float* __restrict__ p_flat,
                                   const int* __restrict__ e_flat,
                                   float* __restrict__ dispatch,
                                   float* __restrict__ combine,
                                   int* __restrict__ counts) {
    __shared__ unsigned long long keys[4096];
    __shared__ int cnt;
    const int tid = threadIdx.x;
    const int e   = blockIdx.x;

    if (tid == 0) cnt = 0;
    __syncthreads();

    for (int i4 = tid; i4 < N2 / 4; i4 += 256) {
        int4 ev = ((const int4*)e_flat)[i4];
        int slot = i4 * 4;
#pragma unroll
        for (int j = 0; j < 4; ++j) {
            int ee = (j == 0) ? ev.x : (j == 1) ? ev.y : (j == 2) ? ev.z : ev.w;
            if (ee == e) {
                float p = p_flat[slot + j];
                int pos = atomicAdd(&cnt, 1);
                if (pos < 4096)
                    keys[pos] = ((unsigned long long)__float_as_uint(p) << 32) |
                                (unsigned long long)(0xFFFFFFFFu - (unsigned)(slot + j));
            }
        }
    }
    __syncthreads();
    const int n = cnt;

    if (n > CAPACITY) {
        int m = 2048;                    // n > 1126 -> m is 2048 or 4096
        while (m < n) m <<= 1;
        for (int i = tid; i < m; i += 256)
            if (i >= n) keys[i] = 0ull;
        __syncthreads();

        for (int k = 2; k <= m; k <<= 1) {
            for (int j = k >> 1; j > 0; j >>= 1) {
                for (int i = tid; i < m; i += 256) {
                    int ixj = i ^ j;
                    if (ixj > i) {
                        bool desc = ((i & k) == 0);
                        unsigned long long a = keys[i], b = keys[ixj];
                        bool sw = desc ? (a < b) : (a > b);
                        if (sw) { keys[i] = b; keys[ixj] = a; }
                    }
                }
                __syncthreads();
            }
        }
    }

    int lim = n < CAPACITY ? n : CAPACITY;
    for (int pos = tid; pos < lim; pos += 256) {
        unsigned long long key = keys[pos];
        unsigned slot = 0xFFFFFFFFu - (unsigned)(key & 0xFFFFFFFFull);
        float p = __uint_as_float((unsigned)(key >> 32));
        int token = (int)(slot >> 1);
        dispatch[(size_t)token * 64 + e] = 1.0f;
        combine [(size_t)token * 64 + e] = p;
    }
    if (tid == 0) counts[e] = n;
}

// ---------------- aux loss ----------------
__global__ void aux_kernel(const float* __restrict__ psum,
                           const int* __restrict__ counts,
                           float* __restrict__ out_aux) {
    int tid = threadIdx.x;   // 64 threads
    float v = (psum[tid] / (float)TOKENS) * ((float)counts[tid] / (float)N2);
    for (int off = 32; off > 0; off >>= 1) v += __shfl_down(v, off, 64);
    if (tid == 0) *out_aux = v * (float)NEXP;
}

extern "C" void kernel_launch(void* const* d_in, const int* in_sizes, int n_in,
                              void* d_out, int out_size, void* d_ws, size_t ws_size,
                              hipStream_t stream) {
    (void)in_sizes; (void)n_in; (void)out_size; (void)ws_size;

    const float* x = (const float*)d_in[0];
    const float* W = (const float*)d_in[1];

    float* out      = (float*)d_out;
    float* dispatch = out;                         // [32768*64]
    float* combine  = out + (size_t)TOKENS * NEXP; // [32768*64]
    float* probs    = out + (size_t)2 * TOKENS * NEXP;
    float* aux      = out + (size_t)3 * TOKENS * NEXP;

    char*  ws     = (char*)d_ws;
    float* part   = (float*)(ws + WS_PART);
    float* p_flat = (float*)(ws + WS_PFLAT);
    int*   e_flat = (int*)  (ws + WS_EFLAT);
    float* psum   = (float*)(ws + WS_PSUM);
    int*   counts = (int*)  (ws + WS_CNT);

    zero_kernel<<<1024, 256, 0, stream>>>(dispatch, psum);
    gemm_logits<<<512, 128, 0, stream>>>(x, W, part);
    combine_kernel<<<256, 256, 0, stream>>>(part, probs, p_flat, e_flat, psum);
    expert_sort_kernel<<<64, 256, 0, stream>>>(p_flat, e_flat, dispatch, combine, counts);
    aux_kernel<<<1, 64, 0, stream>>>(psum, counts, aux);
}